// Round 5
// baseline (1179.281 us; speedup 1.0000x reference)
//
#include <hip/hip_runtime.h>
#include <hip/hip_bf16.h>

#define UNITS 512
#define SEQ   4096
#define BATCH 32

typedef __attribute__((ext_vector_type(8))) __bf16 bf16x8;
typedef __attribute__((ext_vector_type(4))) float  f32x4;

// LDS swizzle for 64B-stride rows: phys = l ^ (((l>>6)&7)<<4). Bijective
// (not an involution; used as the SAME forward map on write and read).
__device__ __forceinline__ int swzB(int l) { return l ^ (((l >> 6) & 7) << 4); }

// ---------------- K0: Uw [k][n] f32 -> UwTt tiled + pre-swizzled bf16 ----------
// 32 tiles of 16KB, tile T = kstep*2 + half. Byte swzB(n_local*64 + c*16) holds
// B-row n_local, k-chunk c (8 bf16). k_logits stages a tile with LINEAR
// contiguous global_load_lds and reads with swzB -> conflict-free.
__global__ void k_bprep(const float* __restrict__ Uw, __bf16* __restrict__ UwTt) {
    const int c     = blockIdx.x;   // k-chunk within step (0..3), 8 elems each
    const int half  = blockIdx.y;   // n half (0..1)
    const int kstep = blockIdx.z;   // 0..15
    const int t     = threadIdx.x;  // n within half (0..255)
    const int n = half * 256 + t;
    bf16x8 o;
#pragma unroll
    for (int j = 0; j < 8; j++)
        o[j] = (__bf16)Uw[(size_t)(kstep * 32 + c * 8 + j) * UNITS + n];
    const int tile = kstep * 2 + half;
    char* dst = (char*)UwTt + (size_t)tile * 16384 + swzB(t * 64 + c * 16);
    *(bf16x8*)dst = o;
}

// ---------------- KA: ws_Ws[b][v] = s_prev[b,:] @ Ww[:,v] + Wb[v] + Ub[v] --------
__global__ void k_wsrow(const float* __restrict__ s_prev, const float* __restrict__ Ww,
                        const float* __restrict__ Wb, const float* __restrict__ Ub,
                        float* __restrict__ ws_Ws) {
    __shared__ float sp[UNITS];
    int b = blockIdx.x, t = threadIdx.x;
    sp[t] = s_prev[b * UNITS + t];
    sp[t + 256] = s_prev[b * UNITS + t + 256];
    __syncthreads();
    float a0 = Wb[t] + Ub[t];
    float a1 = Wb[t + 256] + Ub[t + 256];
#pragma unroll 8
    for (int u = 0; u < UNITS; u++) {
        float s = sp[u];
        a0 += s * Ww[u * UNITS + t];
        a1 += s * Ww[u * UNITS + t + 256];
    }
    ws_Ws[b * UNITS + t] = a0;
    ws_Ws[b * UNITS + t + 256] = a1;
}

// ---------------- KB: fused  tanh(Ws + hidden@Uw) @ Vw  ->  logit partials -------
// grid (2, 1024). 512 thr = 8 waves, wave tile 64x64 (4x4 frags of 16x16x32).
// A: global->reg->cvt(bf16, once per element)->swizzled ds_write.
// B: pre-swizzled global_load_lds. Depth-2 counted-vmcnt pipeline, raw barriers.
#define BM 128
#define BN 256
#define BK 32
#define NSTEP (UNITS / BK)

__launch_bounds__(512, 6)
__global__ void k_logits(const float* __restrict__ hidden, const __bf16* __restrict__ UwTt,
                         const float* __restrict__ wsu, const float* __restrict__ Vw,
                         float* __restrict__ lpart) {
    __shared__ __bf16 Ab[2][BM * BK];   // 8KB per buf, swizzled (swzB)
    __shared__ __bf16 Bb[2][BN * BK];   // 16KB per buf, swizzled (pre-swizzled src)
    __shared__ float  lred[BM][4];      // 2KB   -> total 50KB -> 3 blocks/CU

    const int t = threadIdx.x;
    const int lane = t & 63, wv = t >> 6;
    const int wm = wv >> 2, wn = wv & 3;          // 2 x 4 wave grid
    const int l15 = lane & 15, l4 = lane >> 4;
    const int gx = blockIdx.x;
    const int m0 = blockIdx.y * BM;
    const int b  = m0 >> 12;

    f32x4 acc[4][4];
#pragma unroll
    for (int i = 0; i < 4; i++)
#pragma unroll
        for (int j = 0; j < 4; j++) acc[i][j] = (f32x4){0.f, 0.f, 0.f, 0.f};

    // ---- A staging geometry: 512 thr x 8 f32 = 128 rows x 32 k per step ----
    const int sr = t >> 2;                  // row 0..127
    const int sc = t & 3;                   // 8-elem chunk 0..3
    const float* aRow = hidden + (size_t)(m0 + sr) * UNITS + sc * 8;
    const int aoffW = swzB(sr * 64 + sc * 16);

    int aoffR[4], boffR[4];
#pragma unroll
    for (int f = 0; f < 4; f++) {
        aoffR[f] = swzB((wm * 64 + f * 16 + l15) * 64 + l4 * 16);
        boffR[f] = swzB((wn * 64 + f * 16 + l15) * 64 + l4 * 16);
    }

    auto issueB = [&](int buf, int s) {
        const char* src = (const char*)UwTt + (size_t)(s * 2 + gx) * 16384
                        + wv * 2048 + lane * 16;
        char* dst = (char*)(&Bb[buf][0]) + wv * 2048;
        __builtin_amdgcn_global_load_lds(
            (const __attribute__((address_space(1))) void*)src,
            (__attribute__((address_space(3))) void*)dst, 16, 0, 0);
        __builtin_amdgcn_global_load_lds(
            (const __attribute__((address_space(1))) void*)(src + 1024),
            (__attribute__((address_space(3))) void*)(dst + 1024), 16, 0, 0);
    };

    // named per-parity register state (plain locals, never address-taken)
    float4 ae0, ae1, ao0, ao1;

    // prologue: issue order A0,B0,A1,B1 (vmcnt counting relies on the set, not order)
    ae0 = *(const float4*)(aRow);      ae1 = *(const float4*)(aRow + 4);
    issueB(0, 0);
    ao0 = *(const float4*)(aRow + BK); ao1 = *(const float4*)(aRow + BK + 4);
    issueB(1, 1);

#define STEP(s, AV0, AV1) do {                                                 \
    const int cur = (s) & 1;                                                   \
    bf16x8 o;                                                                  \
    o[0]=(__bf16)AV0.x; o[1]=(__bf16)AV0.y; o[2]=(__bf16)AV0.z; o[3]=(__bf16)AV0.w; \
    o[4]=(__bf16)AV1.x; o[5]=(__bf16)AV1.y; o[6]=(__bf16)AV1.z; o[7]=(__bf16)AV1.w; \
    *(bf16x8*)((char*)(&Ab[cur][0]) + aoffW) = o;                              \
    if ((s) < NSTEP - 1) asm volatile("s_waitcnt vmcnt(4) lgkmcnt(0)" ::: "memory"); \
    else                 asm volatile("s_waitcnt vmcnt(0) lgkmcnt(0)" ::: "memory"); \
    asm volatile("s_barrier" ::: "memory");                                    \
    bf16x8 a[4], bq[4];                                                        \
    _Pragma("unroll") for (int fi = 0; fi < 4; fi++)                           \
        a[fi] = *(const bf16x8*)((const char*)(&Ab[cur][0]) + aoffR[fi]);      \
    _Pragma("unroll") for (int fj = 0; fj < 4; fj++)                           \
        bq[fj] = *(const bf16x8*)((const char*)(&Bb[cur][0]) + boffR[fj]);     \
    asm volatile("s_waitcnt lgkmcnt(0)" ::: "memory");                         \
    __builtin_amdgcn_sched_barrier(0);                                         \
    __builtin_amdgcn_s_setprio(1);                                             \
    _Pragma("unroll") for (int fi = 0; fi < 4; fi++)                           \
        _Pragma("unroll") for (int fj = 0; fj < 4; fj++)                       \
            acc[fi][fj] = __builtin_amdgcn_mfma_f32_16x16x32_bf16(a[fi], bq[fj], acc[fi][fj], 0, 0, 0); \
    __builtin_amdgcn_s_setprio(0);                                             \
    asm volatile("s_barrier" ::: "memory");                                    \
    if ((s) + 2 < NSTEP) {                                                     \
        AV0 = *(const float4*)(aRow + ((s) + 2) * BK);                         \
        AV1 = *(const float4*)(aRow + ((s) + 2) * BK + 4);                     \
        issueB(cur, (s) + 2);                                                  \
    }                                                                          \
} while (0)

    STEP(0,  ae0, ae1);  STEP(1,  ao0, ao1);
    STEP(2,  ae0, ae1);  STEP(3,  ao0, ao1);
    STEP(4,  ae0, ae1);  STEP(5,  ao0, ao1);
    STEP(6,  ae0, ae1);  STEP(7,  ao0, ao1);
    STEP(8,  ae0, ae1);  STEP(9,  ao0, ao1);
    STEP(10, ae0, ae1);  STEP(11, ao0, ao1);
    STEP(12, ae0, ae1);  STEP(13, ao0, ao1);
    STEP(14, ae0, ae1);  STEP(15, ao0, ao1);
#undef STEP

    // epilogue: tanh(acc + Ws+Ub) * Vw, reduce over this block's 256 cols
    float wsub[4], vww[4];
#pragma unroll
    for (int fj = 0; fj < 4; fj++) {
        int n = gx * BN + wn * 64 + fj * 16 + l15;
        wsub[fj] = wsu[b * UNITS + n];
        vww[fj]  = Vw[n];
    }
#pragma unroll
    for (int fi = 0; fi < 4; fi++) {
#pragma unroll
        for (int r = 0; r < 4; r++) {
            float p = 0.f;
#pragma unroll
            for (int fj = 0; fj < 4; fj++) {
                float x = acc[fi][fj][r] + wsub[fj];
                float e = __expf(2.f * x);
                p += vww[fj] * (1.f - 2.f / (e + 1.f));   // tanh(x)
            }
#pragma unroll
            for (int off = 1; off < 16; off <<= 1) p += __shfl_xor(p, off);
            if (l15 == 0) lred[wm * 64 + fi * 16 + l4 * 4 + r][wn] = p;
        }
    }
    __syncthreads();
    if (t < BM) {
        float s = lred[t][0] + lred[t][1] + lred[t][2] + lred[t][3];
        lpart[(size_t)(m0 + t) * 2 + gx] = s;
    }
}

// ---------------- KC: softmax over seq axis, write weights ----------------------
__global__ void k_softmax(const float* __restrict__ lpart, float* __restrict__ wout) {
    __shared__ float ebuf[SEQ];
    __shared__ float red[8];
    int b = blockIdx.x, t = threadIdx.x;
    int lane = t & 63, wv = t >> 6;
    float m = -1e30f;
#pragma unroll
    for (int i = 0; i < 16; i++) {
        int s = t + i * 256;
        size_t idx = ((size_t)b * SEQ + s) * 2;
        float l = lpart[idx] + lpart[idx + 1];
        ebuf[s] = l;
        m = fmaxf(m, l);
    }
#pragma unroll
    for (int off = 32; off >= 1; off >>= 1) m = fmaxf(m, __shfl_xor(m, off));
    if (lane == 0) red[wv] = m;
    __syncthreads();
    m = fmaxf(fmaxf(red[0], red[1]), fmaxf(red[2], red[3]));
    float zs = 0.f;
#pragma unroll
    for (int i = 0; i < 16; i++) {
        int s = t + i * 256;
        float e = __expf(ebuf[s] - m);
        ebuf[s] = e;
        zs += e;
    }
#pragma unroll
    for (int off = 32; off >= 1; off >>= 1) zs += __shfl_xor(zs, off);
    __syncthreads();
    if (lane == 0) red[wv] = zs;
    __syncthreads();
    float inv = 1.f / (red[0] + red[1] + red[2] + red[3]);
#pragma unroll
    for (int i = 0; i < 16; i++) {
        int s = t + i * 256;
        wout[(size_t)b * SEQ + s] = ebuf[s] * inv;
    }
}

// ---------------- KD: context partials over 128-seq chunks ----------------------
__global__ void k_ctxpart(const float* __restrict__ hidden, const float* __restrict__ wout,
                          float* __restrict__ part) {
    int b = blockIdx.y, c = blockIdx.x, t = threadIdx.x;
    const float* w = wout + (size_t)b * SEQ + c * 128;
    const float* h = hidden + ((size_t)b * SEQ + c * 128) * UNITS;
    float2 acc = make_float2(0.f, 0.f);
#pragma unroll 4
    for (int s = 0; s < 128; s++) {
        float ww = w[s];
        float2 v = ((const float2*)(h + (size_t)s * UNITS))[t];
        acc.x += ww * v.x;
        acc.y += ww * v.y;
    }
    ((float2*)(part + ((size_t)(b * 32 + c)) * UNITS))[t] = acc;
}

// ---------------- KE: reduce partials -> context --------------------------------
__global__ void k_ctxreduce(const float* __restrict__ part, float* __restrict__ ctx) {
    int b = blockIdx.x, t = threadIdx.x;
    float s = 0.f;
#pragma unroll
    for (int c = 0; c < 32; c++) s += part[((size_t)(b * 32 + c)) * UNITS + t];
    ctx[(size_t)b * UNITS + t] = s;
}

extern "C" void kernel_launch(void* const* d_in, const int* in_sizes, int n_in,
                              void* d_out, int out_size, void* d_ws, size_t ws_size,
                              hipStream_t stream) {
    const float* s_prev = (const float*)d_in[0];
    const float* hidden = (const float*)d_in[1];
    const float* Ww     = (const float*)d_in[2];
    const float* Wb     = (const float*)d_in[3];
    const float* Uw     = (const float*)d_in[4];
    const float* Ub     = (const float*)d_in[5];
    const float* Vw     = (const float*)d_in[6];
    // d_in[7] = Vb: constant shift, cancels in softmax.

    float* out  = (float*)d_out;
    float* ctx  = out;                    // [32, 512]
    float* wout = out + BATCH * UNITS;    // [32, 4096, 1]

    float* wsf   = (float*)d_ws;
    float* ws_Ws = wsf;                                  // 16384 f32
    float* ws_lp = ws_Ws + BATCH * UNITS;                // 262144 f32
    float* ws_cp = ws_lp + (size_t)BATCH * SEQ * 2;      // 524288 f32
    __bf16* UwTt = (__bf16*)(ws_cp + (size_t)BATCH * 32 * UNITS);  // 512 KB bf16

    k_bprep<<<dim3(4, 2, 16), dim3(256), 0, stream>>>(Uw, UwTt);
    k_wsrow<<<dim3(32), dim3(256), 0, stream>>>(s_prev, Ww, Wb, Ub, ws_Ws);
    k_logits<<<dim3(2, 1024), dim3(512), 0, stream>>>(hidden, UwTt, ws_Ws, Vw, ws_lp);
    k_softmax<<<dim3(32), dim3(256), 0, stream>>>(ws_lp, wout);
    k_ctxpart<<<dim3(32, 32), dim3(256), 0, stream>>>(hidden, wout, ws_cp);
    k_ctxreduce<<<dim3(32), dim3(512), 0, stream>>>(ws_cp, ctx);
}

// Round 6
// 209.594 us; speedup vs baseline: 5.6265x; 5.6265x over previous
//
#include <hip/hip_runtime.h>
#include <hip/hip_bf16.h>

#define UNITS 512
#define SEQ   4096
#define BATCH 32

typedef __attribute__((ext_vector_type(8))) __bf16 bf16x8;
typedef __attribute__((ext_vector_type(4))) float  f32x4;

// LDS swizzle for 64B-stride rows: phys = l ^ (((l>>6)&7)<<4). Bijective;
// used as the SAME forward map on write and read.
__device__ __forceinline__ int swzB(int l) { return l ^ (((l >> 6) & 7) << 4); }

// ---------------- K0: Uw [k][n] f32 -> UwTt tiled + pre-swizzled bf16 ----------
__global__ void k_bprep(const float* __restrict__ Uw, __bf16* __restrict__ UwTt) {
    const int c     = blockIdx.x;   // k-chunk within step (0..3), 8 elems each
    const int half  = blockIdx.y;   // n half (0..1)
    const int kstep = blockIdx.z;   // 0..15
    const int t     = threadIdx.x;  // n within half (0..255)
    const int n = half * 256 + t;
    bf16x8 o;
#pragma unroll
    for (int j = 0; j < 8; j++)
        o[j] = (__bf16)Uw[(size_t)(kstep * 32 + c * 8 + j) * UNITS + n];
    const int tile = kstep * 2 + half;
    char* dst = (char*)UwTt + (size_t)tile * 16384 + swzB(t * 64 + c * 16);
    *(bf16x8*)dst = o;
}

// ---------------- KA: ws_Ws[b][v] = s_prev[b,:] @ Ww[:,v] + Wb[v] + Ub[v] --------
__global__ void k_wsrow(const float* __restrict__ s_prev, const float* __restrict__ Ww,
                        const float* __restrict__ Wb, const float* __restrict__ Ub,
                        float* __restrict__ ws_Ws) {
    __shared__ float sp[UNITS];
    int b = blockIdx.x, t = threadIdx.x;
    sp[t] = s_prev[b * UNITS + t];
    sp[t + 256] = s_prev[b * UNITS + t + 256];
    __syncthreads();
    float a0 = Wb[t] + Ub[t];
    float a1 = Wb[t + 256] + Ub[t + 256];
#pragma unroll 8
    for (int u = 0; u < UNITS; u++) {
        float s = sp[u];
        a0 += s * Ww[u * UNITS + t];
        a1 += s * Ww[u * UNITS + t + 256];
    }
    ws_Ws[b * UNITS + t] = a0;
    ws_Ws[b * UNITS + t + 256] = a1;
}

// ---------------- KB: fused  tanh(Ws + hidden@Uw) @ Vw  ->  logit partials -------
// grid (2, 1024). 512 thr = 8 waves, wave tile 64x64 (4x4 frags of 16x16x32).
// A: global->reg->cvt(bf16 once)->swizzled ds_write.  B: pre-swizzled gll.
// Depth-2 counted-vmcnt pipeline, raw barriers.
// launch_bounds(512,4): VGPR cap 128 (fits ~110, no spill) -> 2 blocks/CU.
// (512,6) spilled acc to scratch: VGPR 40, 8GB scratch traffic, 7x slower.
#define BM 128
#define BN 256
#define BK 32
#define NSTEP (UNITS / BK)

__launch_bounds__(512, 4)
__global__ void k_logits(const float* __restrict__ hidden, const __bf16* __restrict__ UwTt,
                         const float* __restrict__ wsu, const float* __restrict__ Vw,
                         float* __restrict__ lpart) {
    __shared__ __bf16 Ab[2][BM * BK];   // 8KB per buf, swizzled (swzB)
    __shared__ __bf16 Bb[2][BN * BK];   // 16KB per buf, swizzled (pre-swizzled src)
    __shared__ float  lred[BM][4];      // 2KB -> total 50KB

    const int t = threadIdx.x;
    const int lane = t & 63, wv = t >> 6;
    const int wm = wv >> 2, wn = wv & 3;          // 2 x 4 wave grid
    const int l15 = lane & 15, l4 = lane >> 4;
    const int gx = blockIdx.x;
    const int m0 = blockIdx.y * BM;
    const int b  = m0 >> 12;

    f32x4 acc[4][4];
#pragma unroll
    for (int i = 0; i < 4; i++)
#pragma unroll
        for (int j = 0; j < 4; j++) acc[i][j] = (f32x4){0.f, 0.f, 0.f, 0.f};

    // ---- A staging geometry: 512 thr x 8 f32 = 128 rows x 32 k per step ----
    const int sr = t >> 2;                  // row 0..127
    const int sc = t & 3;                   // 8-elem chunk 0..3
    const float* aRow = hidden + (size_t)(m0 + sr) * UNITS + sc * 8;
    const int aoffW = swzB(sr * 64 + sc * 16);

    int aoffR[4], boffR[4];
#pragma unroll
    for (int f = 0; f < 4; f++) {
        aoffR[f] = swzB((wm * 64 + f * 16 + l15) * 64 + l4 * 16);
        boffR[f] = swzB((wn * 64 + f * 16 + l15) * 64 + l4 * 16);
    }

    auto issueB = [&](int buf, int s) {
        const char* src = (const char*)UwTt + (size_t)(s * 2 + gx) * 16384
                        + wv * 2048 + lane * 16;
        char* dst = (char*)(&Bb[buf][0]) + wv * 2048;
        __builtin_amdgcn_global_load_lds(
            (const __attribute__((address_space(1))) void*)src,
            (__attribute__((address_space(3))) void*)dst, 16, 0, 0);
        __builtin_amdgcn_global_load_lds(
            (const __attribute__((address_space(1))) void*)(src + 1024),
            (__attribute__((address_space(3))) void*)(dst + 1024), 16, 0, 0);
    };

    // named per-parity register state (plain locals, never address-taken)
    float4 ae0, ae1, ao0, ao1;

    ae0 = *(const float4*)(aRow);      ae1 = *(const float4*)(aRow + 4);
    issueB(0, 0);
    ao0 = *(const float4*)(aRow + BK); ao1 = *(const float4*)(aRow + BK + 4);
    issueB(1, 1);

#define STEP(s, AV0, AV1) do {                                                 \
    const int cur = (s) & 1;                                                   \
    bf16x8 o;                                                                  \
    o[0]=(__bf16)AV0.x; o[1]=(__bf16)AV0.y; o[2]=(__bf16)AV0.z; o[3]=(__bf16)AV0.w; \
    o[4]=(__bf16)AV1.x; o[5]=(__bf16)AV1.y; o[6]=(__bf16)AV1.z; o[7]=(__bf16)AV1.w; \
    *(bf16x8*)((char*)(&Ab[cur][0]) + aoffW) = o;                              \
    if ((s) < NSTEP - 1) asm volatile("s_waitcnt vmcnt(4) lgkmcnt(0)" ::: "memory"); \
    else                 asm volatile("s_waitcnt vmcnt(0) lgkmcnt(0)" ::: "memory"); \
    asm volatile("s_barrier" ::: "memory");                                    \
    bf16x8 a[4], bq[4];                                                        \
    _Pragma("unroll") for (int fi = 0; fi < 4; fi++)                           \
        a[fi] = *(const bf16x8*)((const char*)(&Ab[cur][0]) + aoffR[fi]);      \
    _Pragma("unroll") for (int fj = 0; fj < 4; fj++)                           \
        bq[fj] = *(const bf16x8*)((const char*)(&Bb[cur][0]) + boffR[fj]);     \
    asm volatile("s_waitcnt lgkmcnt(0)" ::: "memory");                         \
    __builtin_amdgcn_sched_barrier(0);                                         \
    __builtin_amdgcn_s_setprio(1);                                             \
    _Pragma("unroll") for (int fi = 0; fi < 4; fi++)                           \
        _Pragma("unroll") for (int fj = 0; fj < 4; fj++)                       \
            acc[fi][fj] = __builtin_amdgcn_mfma_f32_16x16x32_bf16(a[fi], bq[fj], acc[fi][fj], 0, 0, 0); \
    __builtin_amdgcn_s_setprio(0);                                             \
    asm volatile("s_barrier" ::: "memory");                                    \
    if ((s) + 2 < NSTEP) {                                                     \
        AV0 = *(const float4*)(aRow + ((s) + 2) * BK);                         \
        AV1 = *(const float4*)(aRow + ((s) + 2) * BK + 4);                     \
        issueB(cur, (s) + 2);                                                  \
    }                                                                          \
} while (0)

    STEP(0,  ae0, ae1);  STEP(1,  ao0, ao1);
    STEP(2,  ae0, ae1);  STEP(3,  ao0, ao1);
    STEP(4,  ae0, ae1);  STEP(5,  ao0, ao1);
    STEP(6,  ae0, ae1);  STEP(7,  ao0, ao1);
    STEP(8,  ae0, ae1);  STEP(9,  ao0, ao1);
    STEP(10, ae0, ae1);  STEP(11, ao0, ao1);
    STEP(12, ae0, ae1);  STEP(13, ao0, ao1);
    STEP(14, ae0, ae1);  STEP(15, ao0, ao1);
#undef STEP

    // epilogue: tanh(acc + Ws+Ub) * Vw, reduce over this block's 256 cols
    float wsub[4], vww[4];
#pragma unroll
    for (int fj = 0; fj < 4; fj++) {
        int n = gx * BN + wn * 64 + fj * 16 + l15;
        wsub[fj] = wsu[b * UNITS + n];
        vww[fj]  = Vw[n];
    }
#pragma unroll
    for (int fi = 0; fi < 4; fi++) {
#pragma unroll
        for (int r = 0; r < 4; r++) {
            float p = 0.f;
#pragma unroll
            for (int fj = 0; fj < 4; fj++) {
                float x = acc[fi][fj][r] + wsub[fj];
                float e = __expf(2.f * x);
                p += vww[fj] * (1.f - 2.f / (e + 1.f));   // tanh(x)
            }
#pragma unroll
            for (int off = 1; off < 16; off <<= 1) p += __shfl_xor(p, off);
            if (l15 == 0) lred[wm * 64 + fi * 16 + l4 * 4 + r][wn] = p;
        }
    }
    __syncthreads();
    if (t < BM) {
        float s = lred[t][0] + lred[t][1] + lred[t][2] + lred[t][3];
        lpart[(size_t)(m0 + t) * 2 + gx] = s;
    }
}

// ---------------- KC: softmax over seq axis, write weights ----------------------
__global__ void k_softmax(const float* __restrict__ lpart, float* __restrict__ wout) {
    __shared__ float ebuf[SEQ];
    __shared__ float red[8];
    int b = blockIdx.x, t = threadIdx.x;
    int lane = t & 63, wv = t >> 6;
    float m = -1e30f;
#pragma unroll
    for (int i = 0; i < 16; i++) {
        int s = t + i * 256;
        size_t idx = ((size_t)b * SEQ + s) * 2;
        float l = lpart[idx] + lpart[idx + 1];
        ebuf[s] = l;
        m = fmaxf(m, l);
    }
#pragma unroll
    for (int off = 32; off >= 1; off >>= 1) m = fmaxf(m, __shfl_xor(m, off));
    if (lane == 0) red[wv] = m;
    __syncthreads();
    m = fmaxf(fmaxf(red[0], red[1]), fmaxf(red[2], red[3]));
    float zs = 0.f;
#pragma unroll
    for (int i = 0; i < 16; i++) {
        int s = t + i * 256;
        float e = __expf(ebuf[s] - m);
        ebuf[s] = e;
        zs += e;
    }
#pragma unroll
    for (int off = 32; off >= 1; off >>= 1) zs += __shfl_xor(zs, off);
    __syncthreads();
    if (lane == 0) red[wv] = zs;
    __syncthreads();
    float inv = 1.f / (red[0] + red[1] + red[2] + red[3]);
#pragma unroll
    for (int i = 0; i < 16; i++) {
        int s = t + i * 256;
        wout[(size_t)b * SEQ + s] = ebuf[s] * inv;
    }
}

// ---------------- KD: context partials over 128-seq chunks ----------------------
__global__ void k_ctxpart(const float* __restrict__ hidden, const float* __restrict__ wout,
                          float* __restrict__ part) {
    int b = blockIdx.y, c = blockIdx.x, t = threadIdx.x;
    const float* w = wout + (size_t)b * SEQ + c * 128;
    const float* h = hidden + ((size_t)b * SEQ + c * 128) * UNITS;
    float2 acc = make_float2(0.f, 0.f);
#pragma unroll 4
    for (int s = 0; s < 128; s++) {
        float ww = w[s];
        float2 v = ((const float2*)(h + (size_t)s * UNITS))[t];
        acc.x += ww * v.x;
        acc.y += ww * v.y;
    }
    ((float2*)(part + ((size_t)(b * 32 + c)) * UNITS))[t] = acc;
}

// ---------------- KE: reduce partials -> context --------------------------------
__global__ void k_ctxreduce(const float* __restrict__ part, float* __restrict__ ctx) {
    int b = blockIdx.x, t = threadIdx.x;
    float s = 0.f;
#pragma unroll
    for (int c = 0; c < 32; c++) s += part[((size_t)(b * 32 + c)) * UNITS + t];
    ctx[(size_t)b * UNITS + t] = s;
}

extern "C" void kernel_launch(void* const* d_in, const int* in_sizes, int n_in,
                              void* d_out, int out_size, void* d_ws, size_t ws_size,
                              hipStream_t stream) {
    const float* s_prev = (const float*)d_in[0];
    const float* hidden = (const float*)d_in[1];
    const float* Ww     = (const float*)d_in[2];
    const float* Wb     = (const float*)d_in[3];
    const float* Uw     = (const float*)d_in[4];
    const float* Ub     = (const float*)d_in[5];
    const float* Vw     = (const float*)d_in[6];
    // d_in[7] = Vb: constant shift, cancels in softmax.

    float* out  = (float*)d_out;
    float* ctx  = out;                    // [32, 512]
    float* wout = out + BATCH * UNITS;    // [32, 4096, 1]

    float* wsf   = (float*)d_ws;
    float* ws_Ws = wsf;                                  // 16384 f32
    float* ws_lp = ws_Ws + BATCH * UNITS;                // 262144 f32
    float* ws_cp = ws_lp + (size_t)BATCH * SEQ * 2;      // 524288 f32
    __bf16* UwTt = (__bf16*)(ws_cp + (size_t)BATCH * 32 * UNITS);  // 512 KB bf16

    k_bprep<<<dim3(4, 2, 16), dim3(256), 0, stream>>>(Uw, UwTt);
    k_wsrow<<<dim3(32), dim3(256), 0, stream>>>(s_prev, Ww, Wb, Ub, ws_Ws);
    k_logits<<<dim3(2, 1024), dim3(512), 0, stream>>>(hidden, UwTt, ws_Ws, Vw, ws_lp);
    k_softmax<<<dim3(32), dim3(256), 0, stream>>>(ws_lp, wout);
    k_ctxpart<<<dim3(32, 32), dim3(256), 0, stream>>>(hidden, wout, ws_cp);
    k_ctxreduce<<<dim3(32), dim3(512), 0, stream>>>(ws_cp, ctx);
}